// Round 6
// baseline (520.617 us; speedup 1.0000x reference)
//
#include <hip/hip_runtime.h>
#include <hip/hip_bf16.h>
#include <hip/hip_cooperative_groups.h>

namespace cg = cooperative_groups;

// Problem constants
#define B    32
#define P    576     // 24*24 patches
#define D    768
#define K1   17      // K+1 prototypes
#define KFG  16
#define C    200
#define LN_EPS 1e-6f

typedef __attribute__((ext_vector_type(8))) short short8;   // 8 bf16 (4 VGPRs)
typedef __attribute__((ext_vector_type(4))) float f32x4;

__device__ inline unsigned short f2b(float f) {   // fp32 -> bf16 RNE (scalar)
    union { float f; unsigned u; } x; x.f = f;
    unsigned r = x.u + 0x7FFF + ((x.u >> 16) & 1);
    return (unsigned short)(r >> 16);
}

// packed fp32x8 -> bf16x8 via v_cvt_pk_bf16_f32
__device__ inline short8 cvt8(float4 a, float4 b) {
    union { unsigned u[4]; short8 s; } r;
    union { __hip_bfloat162 h; unsigned u; } c;
    c.h = __float22bfloat162_rn(make_float2(a.x, a.y)); r.u[0] = c.u;
    c.h = __float22bfloat162_rn(make_float2(a.z, a.w)); r.u[1] = c.u;
    c.h = __float22bfloat162_rn(make_float2(b.x, b.y)); r.u[2] = c.u;
    c.h = __float22bfloat162_rn(make_float2(b.z, b.w)); r.u[3] = c.u;
    return r.s;
}

// ================= ONE cooperative kernel, 6 phases, 5 grid syncs =================
// grid 256 x 256 threads: 1 block/CU guaranteed co-resident at any VGPR count.
__global__ __launch_bounds__(256, 1) void k_all(
        const float* __restrict__ x, const float* __restrict__ proto,
        const float* __restrict__ gamma, const float* __restrict__ beta,
        const float* __restrict__ W, const float* __restrict__ bcls,
        float* __restrict__ A_out, float* __restrict__ vnorm_out,
        float* __restrict__ parts_out, float* __restrict__ agg_out,
        float* __restrict__ psq, unsigned short* __restrict__ pbf,
        float* __restrict__ apool, float* __restrict__ vpart,
        float* __restrict__ vT, float* __restrict__ lpart) {
    cg::grid_group grid = cg::this_grid();
    __shared__ float sred[8];

    const int gid = blockIdx.x, t = threadIdx.x;
    const int wv = t >> 6, lane = t & 63;

    // ---------- P0: proto fp32 -> bf16 + psq (blocks 0..16) ----------
    if (gid < K1) {
        const int k = gid;
        float a0 = proto[k * D + t], a1 = proto[k * D + t + 256], a2 = proto[k * D + t + 512];
        pbf[k * D + t]       = f2b(a0);
        pbf[k * D + t + 256] = f2b(a1);
        pbf[k * D + t + 512] = f2b(a2);
        float s = a0 * a0 + a1 * a1 + a2 * a2;
        #pragma unroll
        for (int o = 1; o < 64; o <<= 1) s += __shfl_xor(s, o, 64);
        if (lane == 0) sred[wv] = s;
        __syncthreads();
        if (t == 0) psq[k] = sred[0] + sred[1] + sred[2] + sred[3];
    }
    __threadfence();
    grid.sync();

    // ---------- P1: dots (bf16 MFMA) + softmax; 1152 wave-units ----------
    {
        const int n = lane & 15, kq = lane >> 4;
        for (int u = gid * 4 + wv; u < 1152; u += 1024) {
            const int tile = u % 36, b = u / 36;
            const int p0 = tile * 16;

            const float*          arow = x   + ((size_t)(b * P + p0 + n)) * D + kq * 8;
            const unsigned short* brow = pbf + (size_t)n  * D + kq * 8;
            const unsigned short* brw6 = pbf + (size_t)16 * D + kq * 8;

            f32x4 acc0 = {0.f, 0.f, 0.f, 0.f};
            f32x4 acc1 = {0.f, 0.f, 0.f, 0.f};

            #pragma unroll 8
            for (int s = 0; s < 24; ++s) {
                const float* ap = arow + s * 32;
                float4 v0 = *(const float4*)(ap);
                float4 v1 = *(const float4*)(ap + 4);
                short8 A  = cvt8(v0, v1);
                short8 Bv = *(const short8*)(brow + s * 32);
                short8 B6 = *(const short8*)(brw6 + s * 32);
                acc0 = __builtin_amdgcn_mfma_f32_16x16x32_bf16(A, Bv, acc0, 0, 0, 0);
                acc1 = __builtin_amdgcn_mfma_f32_16x16x32_bf16(A, B6, acc1, 0, 0, 0);
            }

            const float pq = psq[n], pq16 = psq[16];
            float a_[4], a16[4];
            #pragma unroll
            for (int r = 0; r < 4; ++r) {
                float l0  = 2.f * acc0[r] - pq;
                float l16 = 2.f * acc1[r] - pq16;
                float mx = l0;
                #pragma unroll
                for (int o = 1; o < 16; o <<= 1) mx = fmaxf(mx, __shfl_xor(mx, o, 64));
                mx = fmaxf(mx, l16);
                float e0  = __expf(l0 - mx);
                float e16 = __expf(l16 - mx);
                float sum = e0;
                #pragma unroll
                for (int o = 1; o < 16; o <<= 1) sum += __shfl_xor(sum, o, 64);
                sum += e16;
                const float inv = 1.f / sum;
                a_[r]  = e0 * inv;
                a16[r] = e16 * inv;
            }

            *(float4*)(A_out + ((size_t)b * K1 + n) * P + p0 + kq * 4) =
                make_float4(a_[0], a_[1], a_[2], a_[3]);
            if (n == 0)
                *(float4*)(A_out + ((size_t)b * K1 + 16) * P + p0 + kq * 4) =
                    make_float4(a16[0], a16[1], a16[2], a16[3]);

            const float invP = 1.f / (float)P;
            #pragma unroll
            for (int r = 0; r < 4; ++r)
                apool[((size_t)b * P + p0 + kq * 4 + r) * KFG + n] = a_[r] * invP;
        }
    }
    __threadfence();
    grid.sync();
    __threadfence();

    // ---------- P2: fp32 pooling; 768 units (3 dchunk x 8 psplit x 32 b), 3/block ----------
    {
        for (int u = gid; u < 768; u += 256) {
            const int dc = u % 3, rem = u / 3;
            const int psl = rem & 7, b = rem >> 3;
            const int d = dc * 256 + t;

            const float* aw = apool + ((size_t)b * P + psl * 72) * KFG;   // wave-uniform
            const float* xp = x + ((size_t)b * P + psl * 72) * D + d;

            float acc[KFG];
            #pragma unroll
            for (int k = 0; k < KFG; ++k) acc[k] = 0.f;

            #pragma unroll 4
            for (int p = 0; p < 72; ++p) {
                float xv = xp[(size_t)p * D];
                f32x4 A0 = *(const f32x4*)(aw + p * 16);
                f32x4 A1 = *(const f32x4*)(aw + p * 16 + 4);
                f32x4 A2 = *(const f32x4*)(aw + p * 16 + 8);
                f32x4 A3 = *(const f32x4*)(aw + p * 16 + 12);
                acc[0]  += A0[0] * xv; acc[1]  += A0[1] * xv; acc[2]  += A0[2] * xv; acc[3]  += A0[3] * xv;
                acc[4]  += A1[0] * xv; acc[5]  += A1[1] * xv; acc[6]  += A1[2] * xv; acc[7]  += A1[3] * xv;
                acc[8]  += A2[0] * xv; acc[9]  += A2[1] * xv; acc[10] += A2[2] * xv; acc[11] += A2[3] * xv;
                acc[12] += A3[0] * xv; acc[13] += A3[1] * xv; acc[14] += A3[2] * xv; acc[15] += A3[3] * xv;
            }
            float* o = vpart + ((size_t)(psl * B + b) * KFG) * D + d;
            #pragma unroll
            for (int k = 0; k < KFG; ++k) o[(size_t)k * D] = acc[k];
        }
    }
    __threadfence();
    grid.sync();
    __threadfence();

    // ---------- P3: reduce 8 p-splits + LayerNorm; 512 units (16 k x 32 b), 2/block ----------
    {
        for (int rep = 0; rep < 2; ++rep) {
            const int u = gid + rep * 256;
            const int k = u & 15, b = u >> 4;

            float v[3]; float s1 = 0.f, s2 = 0.f;
            #pragma unroll
            for (int j = 0; j < 3; ++j) {
                const int d = t + j * 256;
                float s = 0.f;
                #pragma unroll
                for (int psl = 0; psl < 8; ++psl)
                    s += vpart[((size_t)(psl * B + b) * KFG + k) * D + d];
                v[j] = s; s1 += s; s2 += s * s;
            }
            #pragma unroll
            for (int o = 1; o < 64; o <<= 1) {
                s1 += __shfl_xor(s1, o, 64);
                s2 += __shfl_xor(s2, o, 64);
            }
            if (lane == 0) { sred[wv] = s1; sred[4 + wv] = s2; }
            __syncthreads();
            s1 = sred[0] + sred[1] + sred[2] + sred[3];
            s2 = sred[4] + sred[5] + sred[6] + sred[7];
            __syncthreads();   // protect sred before next rep overwrites

            const float mean = s1 * (1.f / (float)D);
            const float var  = s2 * (1.f / (float)D) - mean * mean;
            const float rs   = rsqrtf(var + LN_EPS);

            #pragma unroll
            for (int j = 0; j < 3; ++j) {
                const int d = t + j * 256;
                float vn = (v[j] - mean) * rs * gamma[d] + beta[d];
                vnorm_out[((size_t)b * KFG + k) * D + d] = vn;
                vT[((size_t)b * D + d) * KFG + k] = vn;   // k-contiguous for P4 s_loads
            }
        }
    }
    __threadfence();
    grid.sync();
    __threadfence();

    // ---------- P4: classifier partial GEMV; 256 units (8 dq x 32 b), 1/block ----------
    {
        const int dq = gid & 7, b = gid >> 3;
        const int c = t;
        const int cc = c < C ? c : (C - 1);

        const float* vt = vT + ((size_t)b * D + dq * 96) * KFG;   // wave-uniform rows
        const float* Wp = W + (size_t)dq * 96 * C + cc;

        float acc[KFG];
        #pragma unroll
        for (int k = 0; k < KFG; ++k) acc[k] = 0.f;

        #pragma unroll 4
        for (int i = 0; i < 96; ++i) {
            float wl = Wp[(size_t)i * C];
            f32x4 V0 = *(const f32x4*)(vt + i * 16);
            f32x4 V1 = *(const f32x4*)(vt + i * 16 + 4);
            f32x4 V2 = *(const f32x4*)(vt + i * 16 + 8);
            f32x4 V3 = *(const f32x4*)(vt + i * 16 + 12);
            acc[0]  += V0[0] * wl; acc[1]  += V0[1] * wl; acc[2]  += V0[2] * wl; acc[3]  += V0[3] * wl;
            acc[4]  += V1[0] * wl; acc[5]  += V1[1] * wl; acc[6]  += V1[2] * wl; acc[7]  += V1[3] * wl;
            acc[8]  += V2[0] * wl; acc[9]  += V2[1] * wl; acc[10] += V2[2] * wl; acc[11] += V2[3] * wl;
            acc[12] += V3[0] * wl; acc[13] += V3[1] * wl; acc[14] += V3[2] * wl; acc[15] += V3[3] * wl;
        }
        if (c < C) {
            float* o = lpart + ((size_t)(dq * B + b) * KFG) * C + c;
            #pragma unroll
            for (int k = 0; k < KFG; ++k) o[(size_t)k * C] = acc[k];
        }
    }
    __threadfence();
    grid.sync();
    __threadfence();

    // ---------- P5: combine + bias; 32 units ----------
    if (gid < B) {
        const int b = gid, c = t;
        if (c < C) {
            const float bc = bcls[c];
            float s_agg = 0.f;
            #pragma unroll
            for (int k = 0; k < KFG; ++k) {
                float s = bc;
                #pragma unroll
                for (int dq = 0; dq < 8; ++dq)
                    s += lpart[((size_t)(dq * B + b) * KFG + k) * C + c];
                parts_out[((size_t)b * KFG + k) * C + c] = s;
                s_agg += s;
            }
            agg_out[(size_t)b * C + c] = s_agg * (1.f / (float)KFG);
        }
    }
}

extern "C" void kernel_launch(void* const* d_in, const int* in_sizes, int n_in,
                              void* d_out, int out_size, void* d_ws, size_t ws_size,
                              hipStream_t stream) {
    const float* x     = (const float*)d_in[0];   // (32,24,24,768)
    const float* proto = (const float*)d_in[1];   // (17,768)
    const float* gamma = (const float*)d_in[2];   // (768)
    const float* beta  = (const float*)d_in[3];   // (768)
    const float* W     = (const float*)d_in[4];   // (768,200)
    const float* bcls  = (const float*)d_in[5];   // (200)

    float* out = (float*)d_out;
    float* A_out     = out;                       // 32*17*576   = 313344
    float* vnorm_out = out + 313344;              // 32*16*768   = 393216
    float* parts_out = out + 706560;              // 32*16*200   = 102400
    float* agg_out   = out + 808960;              // 32*200      = 6400

    float* ws = (float*)d_ws;
    float* psq  = ws;                                  // 17 (pad 32)
    unsigned short* pbf = (unsigned short*)(ws + 32);  // 17*768 bf16 (reserve 6528 floats)
    float* apool = ws + 32 + 6528;                     // 32*576*16   = 294912
    float* vpart = apool + 294912;                     // 8*32*16*768 = 3145728
    float* vT    = vpart + 3145728;                    // 32*768*16   = 393216
    float* lpart = vT + 393216;                        // 8*32*16*200 = 819200

    void* args[] = { (void*)&x, (void*)&proto, (void*)&gamma, (void*)&beta,
                     (void*)&W, (void*)&bcls,
                     (void*)&A_out, (void*)&vnorm_out, (void*)&parts_out, (void*)&agg_out,
                     (void*)&psq, (void*)&pbf, (void*)&apool, (void*)&vpart,
                     (void*)&vT, (void*)&lpart };
    hipLaunchCooperativeKernel((void*)k_all, dim3(256), dim3(256), args, 0, stream);
}

// Round 7
// 195.912 us; speedup vs baseline: 2.6574x; 2.6574x over previous
//
#include <hip/hip_runtime.h>
#include <hip/hip_bf16.h>

// Problem constants
#define B    32
#define P    576     // 24*24 patches
#define D    768
#define K1   17      // K+1 prototypes
#define KFG  16
#define C    200
#define LN_EPS 1e-6f

typedef __attribute__((ext_vector_type(8))) short short8;   // 8 bf16 (4 VGPRs)
typedef __attribute__((ext_vector_type(4))) float f32x4;

// packed fp32x8 -> bf16x8 via v_cvt_pk_bf16_f32
__device__ inline short8 cvt8(float4 a, float4 b) {
    union { unsigned u[4]; short8 s; } r;
    union { __hip_bfloat162 h; unsigned u; } c;
    c.h = __float22bfloat162_rn(make_float2(a.x, a.y)); r.u[0] = c.u;
    c.h = __float22bfloat162_rn(make_float2(a.z, a.w)); r.u[1] = c.u;
    c.h = __float22bfloat162_rn(make_float2(b.x, b.y)); r.u[2] = c.u;
    c.h = __float22bfloat162_rn(make_float2(b.z, b.w)); r.u[3] = c.u;
    return r.s;
}
__device__ inline float sq8(float4 a, float4 b) {
    return a.x*a.x + a.y*a.y + a.z*a.z + a.w*a.w
         + b.x*b.x + b.y*b.y + b.z*b.z + b.w*b.w;
}

// ================= K1: dots (bf16 MFMA) + softmax + pooling, fused =================
// grid (9 psplit, 32 b) x 256 (4 waves). Wave wv owns tile = psl*4+wv (16 patches,
// full K=768). Protos converted fp32->bf16 in-register; psq accumulated in-loop
// from the fp32 values (no k_pre). Pool phase re-reads x (L2/L3-hot) and writes
// deterministic vpart[9] slices. Block (0,0) zeroes K2's flags/tickets.
__global__ __launch_bounds__(256) void k_front(const float* __restrict__ x,
                                               const float* __restrict__ proto,
                                               float* __restrict__ A_out,
                                               float* __restrict__ vpart,
                                               int* __restrict__ flags) {
    __shared__ float as_[64 * 16];   // a/P, [block-local patch][k], 4 KB
    const int psl = blockIdx.x, b = blockIdx.y;
    const int t = threadIdx.x, wv = t >> 6, lane = t & 63;
    const int n = lane & 15, kq = lane >> 4;
    const int p0 = psl * 64 + wv * 16;          // tile base (tile = psl*4+wv)

    if (psl == 0 && b == 0 && t < 64) flags[t] = 0;   // [0..31] LN flag, [32..63] ticket

    const float* arow = x     + ((size_t)(b * P + p0 + n)) * D + kq * 8;
    const float* brow = proto + (size_t)n  * D + kq * 8;
    const float* brw6 = proto + (size_t)16 * D + kq * 8;

    f32x4 acc0 = {0.f, 0.f, 0.f, 0.f};   // protos 0..15
    f32x4 acc1 = {0.f, 0.f, 0.f, 0.f};   // proto 16 (broadcast B)
    float sq0 = 0.f, sq6 = 0.f;          // in-loop psq partials (fp32-exact)

    #pragma unroll 8
    for (int s = 0; s < 24; ++s) {
        float4 a0 = *(const float4*)(arow + s * 32);
        float4 a1 = *(const float4*)(arow + s * 32 + 4);
        float4 b0 = *(const float4*)(brow + s * 32);
        float4 b1 = *(const float4*)(brow + s * 32 + 4);
        float4 c0 = *(const float4*)(brw6 + s * 32);
        float4 c1 = *(const float4*)(brw6 + s * 32 + 4);
        short8 A  = cvt8(a0, a1);
        short8 Bv = cvt8(b0, b1);
        short8 B6 = cvt8(c0, c1);
        sq0 += sq8(b0, b1);
        sq6 += sq8(c0, c1);
        acc0 = __builtin_amdgcn_mfma_f32_16x16x32_bf16(A, Bv, acc0, 0, 0, 0);
        acc1 = __builtin_amdgcn_mfma_f32_16x16x32_bf16(A, B6, acc1, 0, 0, 0);
    }
    // psq: sum the 4 kq-quads (lanes n, n+16, n+32, n+48 share proto n)
    sq0 += __shfl_xor(sq0, 16, 64); sq0 += __shfl_xor(sq0, 32, 64);
    sq6 += __shfl_xor(sq6, 16, 64); sq6 += __shfl_xor(sq6, 32, 64);

    // ---- softmax per (kq, r) across n (xor 1,2,4,8 stays within quad) ----
    float a_[4], a16[4];
    #pragma unroll
    for (int r = 0; r < 4; ++r) {
        float l0  = 2.f * acc0[r] - sq0;
        float l16 = 2.f * acc1[r] - sq6;
        float mx = l0;
        #pragma unroll
        for (int o = 1; o < 16; o <<= 1) mx = fmaxf(mx, __shfl_xor(mx, o, 64));
        mx = fmaxf(mx, l16);
        float e0  = __expf(l0 - mx);
        float e16 = __expf(l16 - mx);
        float sum = e0;
        #pragma unroll
        for (int o = 1; o < 16; o <<= 1) sum += __shfl_xor(sum, o, 64);
        sum += e16;
        const float inv = 1.f / sum;
        a_[r]  = e0 * inv;
        a16[r] = e16 * inv;
    }

    *(float4*)(A_out + ((size_t)b * K1 + n) * P + p0 + kq * 4) =
        make_float4(a_[0], a_[1], a_[2], a_[3]);
    if (n == 0)
        *(float4*)(A_out + ((size_t)b * K1 + 16) * P + p0 + kq * 4) =
            make_float4(a16[0], a16[1], a16[2], a16[3]);

    const float invP = 1.f / (float)P;
    #pragma unroll
    for (int r = 0; r < 4; ++r)
        as_[(wv * 16 + kq * 4 + r) * KFG + n] = a_[r] * invP;
    __syncthreads();

    // ---- pool phase: thread owns d = t, t+256, t+512; 64 block-local patches ----
    float accp[3][KFG];
    #pragma unroll
    for (int j = 0; j < 3; ++j)
        #pragma unroll
        for (int k = 0; k < KFG; ++k) accp[j][k] = 0.f;

    const float* xb = x + ((size_t)(b * P + psl * 64)) * D;
    for (int p = 0; p < 64; ++p) {
        f32x4 A0 = *(const f32x4*)(as_ + p * 16);
        f32x4 A1 = *(const f32x4*)(as_ + p * 16 + 4);
        f32x4 A2 = *(const f32x4*)(as_ + p * 16 + 8);
        f32x4 A3 = *(const f32x4*)(as_ + p * 16 + 12);
        float av[KFG] = { A0[0],A0[1],A0[2],A0[3], A1[0],A1[1],A1[2],A1[3],
                          A2[0],A2[1],A2[2],A2[3], A3[0],A3[1],A3[2],A3[3] };
        #pragma unroll
        for (int j = 0; j < 3; ++j) {
            float xv = xb[(size_t)p * D + t + j * 256];
            #pragma unroll
            for (int k = 0; k < KFG; ++k) accp[j][k] += av[k] * xv;
        }
    }
    float* o = vpart + ((size_t)(psl * B + b) * KFG) * D;
    #pragma unroll
    for (int j = 0; j < 3; ++j)
        #pragma unroll
        for (int k = 0; k < KFG; ++k)
            o[(size_t)k * D + t + j * 256] = accp[j][k];
}

// ================= K2: LN (per-b owner block) -> flag -> cls -> ticket -> comb ===========
// grid 256 = (8 dq, 32 b) x 256 threads, all co-resident (point-to-point sync only).
__global__ __launch_bounds__(256) void k_back(const float* __restrict__ vpart,
                                              const float* __restrict__ gamma,
                                              const float* __restrict__ beta,
                                              const float* __restrict__ W,
                                              const float* __restrict__ bcls,
                                              float* __restrict__ vnorm_out,
                                              float* __restrict__ vT,
                                              float* __restrict__ lpart,
                                              float* __restrict__ parts_out,
                                              float* __restrict__ agg_out,
                                              int* __restrict__ flags) {
    const int dq = blockIdx.x & 7, b = blockIdx.x >> 3;
    const int t = threadIdx.x, wv = t >> 6, lane = t & 63;
    int* lnflag = flags;         // [32]
    int* ticket = flags + 32;    // [32]

    if (dq == 0) {
        // ---- LN for b: wave wv owns k = wv*4..wv*4+3; 64-lane reduce, no barriers ----
        #pragma unroll
        for (int kk = 0; kk < 4; ++kk) {
            const int k = wv * 4 + kk;
            float v[12]; float s1 = 0.f, s2 = 0.f;
            #pragma unroll
            for (int i = 0; i < 12; ++i) {
                const int d = i * 64 + lane;
                float s = 0.f;
                #pragma unroll
                for (int psl = 0; psl < 9; ++psl)
                    s += vpart[((size_t)(psl * B + b) * KFG + k) * D + d];
                v[i] = s; s1 += s; s2 += s * s;
            }
            #pragma unroll
            for (int o = 1; o < 64; o <<= 1) {
                s1 += __shfl_xor(s1, o, 64);
                s2 += __shfl_xor(s2, o, 64);
            }
            const float mean = s1 * (1.f / (float)D);
            const float var  = s2 * (1.f / (float)D) - mean * mean;
            const float rs   = rsqrtf(var + LN_EPS);
            #pragma unroll
            for (int i = 0; i < 12; ++i) {
                const int d = i * 64 + lane;
                float vn = (v[i] - mean) * rs * gamma[d] + beta[d];
                vnorm_out[((size_t)b * KFG + k) * D + d] = vn;
                vT[((size_t)b * D + d) * KFG + k] = vn;
            }
        }
        __syncthreads();
        if (t == 0) {
            __builtin_amdgcn_fence(__ATOMIC_RELEASE, "agent");
            __hip_atomic_store(&lnflag[b], 1, __ATOMIC_RELAXED, __HIP_MEMORY_SCOPE_AGENT);
        }
    } else {
        if (t == 0) {
            while (__hip_atomic_load(&lnflag[b], __ATOMIC_RELAXED,
                                     __HIP_MEMORY_SCOPE_AGENT) == 0)
                __builtin_amdgcn_s_sleep(8);
        }
        __syncthreads();
        __builtin_amdgcn_fence(__ATOMIC_ACQUIRE, "agent");
    }

    // ---- cls for (dq, b): thread = class c; vT rows via uniform s_loads ----
    const int c = t;
    const int cc = c < C ? c : (C - 1);
    const float* vt = vT + ((size_t)b * D + dq * 96) * KFG;
    const float* Wp = W + (size_t)dq * 96 * C + cc;

    float acc[KFG];
    #pragma unroll
    for (int k = 0; k < KFG; ++k) acc[k] = 0.f;

    #pragma unroll 4
    for (int i = 0; i < 96; ++i) {
        float wl = Wp[(size_t)i * C];
        f32x4 V0 = *(const f32x4*)(vt + i * 16);
        f32x4 V1 = *(const f32x4*)(vt + i * 16 + 4);
        f32x4 V2 = *(const f32x4*)(vt + i * 16 + 8);
        f32x4 V3 = *(const f32x4*)(vt + i * 16 + 12);
        acc[0]  += V0[0] * wl; acc[1]  += V0[1] * wl; acc[2]  += V0[2] * wl; acc[3]  += V0[3] * wl;
        acc[4]  += V1[0] * wl; acc[5]  += V1[1] * wl; acc[6]  += V1[2] * wl; acc[7]  += V1[3] * wl;
        acc[8]  += V2[0] * wl; acc[9]  += V2[1] * wl; acc[10] += V2[2] * wl; acc[11] += V2[3] * wl;
        acc[12] += V3[0] * wl; acc[13] += V3[1] * wl; acc[14] += V3[2] * wl; acc[15] += V3[3] * wl;
    }
    if (c < C) {
        float* o = lpart + ((size_t)(dq * B + b) * KFG) * C + c;
        #pragma unroll
        for (int k = 0; k < KFG; ++k) o[(size_t)k * C] = acc[k];
    }
    __syncthreads();

    // ---- ticket: 8th finisher for this b combines ----
    __shared__ int swin;
    if (t == 0) {
        __builtin_amdgcn_fence(__ATOMIC_RELEASE, "agent");
        swin = __hip_atomic_fetch_add(&ticket[b], 1, __ATOMIC_RELAXED,
                                      __HIP_MEMORY_SCOPE_AGENT);
    }
    __syncthreads();
    if (swin == 7) {
        __builtin_amdgcn_fence(__ATOMIC_ACQUIRE, "agent");
        if (c < C) {
            const float bc = bcls[c];
            float s_agg = 0.f;
            #pragma unroll
            for (int k = 0; k < KFG; ++k) {
                float s = bc;
                #pragma unroll
                for (int q = 0; q < 8; ++q)
                    s += lpart[((size_t)(q * B + b) * KFG + k) * C + c];
                parts_out[((size_t)b * KFG + k) * C + c] = s;
                s_agg += s;
            }
            agg_out[(size_t)b * C + c] = s_agg * (1.f / (float)KFG);
        }
    }
}

extern "C" void kernel_launch(void* const* d_in, const int* in_sizes, int n_in,
                              void* d_out, int out_size, void* d_ws, size_t ws_size,
                              hipStream_t stream) {
    const float* x     = (const float*)d_in[0];   // (32,24,24,768)
    const float* proto = (const float*)d_in[1];   // (17,768)
    const float* gamma = (const float*)d_in[2];   // (768)
    const float* beta  = (const float*)d_in[3];   // (768)
    const float* W     = (const float*)d_in[4];   // (768,200)
    const float* bcls  = (const float*)d_in[5];   // (200)

    float* out = (float*)d_out;
    float* A_out     = out;                       // 32*17*576   = 313344
    float* vnorm_out = out + 313344;              // 32*16*768   = 393216
    float* parts_out = out + 706560;              // 32*16*200   = 102400
    float* agg_out   = out + 808960;              // 32*200      = 6400

    float* ws = (float*)d_ws;
    float* vpart = ws;                             // 9*32*16*768 = 3538944
    float* vT    = vpart + 3538944;                // 32*768*16   = 393216
    float* lpart = vT + 393216;                    // 8*32*16*200 = 819200
    int*   flags = (int*)(lpart + 819200);         // 64 ints

    hipLaunchKernelGGL(k_front, dim3(9, B), dim3(256), 0, stream,
                       x, proto, A_out, vpart, flags);
    hipLaunchKernelGGL(k_back,  dim3(256),  dim3(256), 0, stream,
                       vpart, gamma, beta, W, bcls,
                       vnorm_out, vT, lpart, parts_out, agg_out, flags);
}

// Round 8
// 184.848 us; speedup vs baseline: 2.8165x; 1.0599x over previous
//
#include <hip/hip_runtime.h>
#include <hip/hip_bf16.h>

// Problem constants
#define B    32
#define P    576     // 24*24 patches
#define D    768
#define K1   17      // K+1 prototypes
#define KFG  16
#define C    200
#define LN_EPS 1e-6f

typedef __attribute__((ext_vector_type(8))) short short8;   // 8 bf16 (4 VGPRs)
typedef __attribute__((ext_vector_type(4))) float f32x4;

// packed fp32x8 -> bf16x8 via v_cvt_pk_bf16_f32
__device__ inline short8 cvt8(float4 a, float4 b) {
    union { unsigned u[4]; short8 s; } r;
    union { __hip_bfloat162 h; unsigned u; } c;
    c.h = __float22bfloat162_rn(make_float2(a.x, a.y)); r.u[0] = c.u;
    c.h = __float22bfloat162_rn(make_float2(a.z, a.w)); r.u[1] = c.u;
    c.h = __float22bfloat162_rn(make_float2(b.x, b.y)); r.u[2] = c.u;
    c.h = __float22bfloat162_rn(make_float2(b.z, b.w)); r.u[3] = c.u;
    return r.s;
}
__device__ inline float sq8(float4 a, float4 b) {
    return a.x*a.x + a.y*a.y + a.z*a.z + a.w*a.w
         + b.x*b.x + b.y*b.y + b.z*b.z + b.w*b.w;
}

// ================= K1: dots (bf16 MFMA, K-split 2) + softmax + pooling =================
// grid (18 psplit, 32 b) x 256 (4 waves). Waves 0,1 = tile0 K-halves; waves 2,3 =
// tile1 K-halves (tiles of 16 patches; block covers 32 patches). 2304 waves total
// -> ~9 waves/CU (vs 4 in R7): latency-bound regime, 2x the in-flight bytes.
// LDS 13.3 KB. psq computed in-loop from fp32 protos. Pool re-reads x (L3-hot).
__global__ __launch_bounds__(256) void k_front(const float* __restrict__ x,
                                               const float* __restrict__ proto,
                                               float* __restrict__ A_out,
                                               float* __restrict__ vpart) {
    __shared__ float scL[4 * 64 * 11];   // [wave][lane][acc0:4|acc1:4|sq0|sq6], stride 11
    __shared__ float as_[32 * 16];       // a/P for pool, [local patch][k]
    const int psl = blockIdx.x, b = blockIdx.y;
    const int t = threadIdx.x, wv = t >> 6, lane = t & 63;
    const int n = lane & 15, kq = lane >> 4;
    const int tilesel = wv >> 1, khalf = wv & 1;
    const int p0 = psl * 32 + tilesel * 16;

    const float* arow = x     + ((size_t)(b * P + p0 + n)) * D + khalf * 384 + kq * 8;
    const float* brow = proto + (size_t)n  * D + khalf * 384 + kq * 8;
    const float* brw6 = proto + (size_t)16 * D + khalf * 384 + kq * 8;

    f32x4 acc0 = {0.f, 0.f, 0.f, 0.f};   // protos 0..15, this K-half
    f32x4 acc1 = {0.f, 0.f, 0.f, 0.f};   // proto 16
    float sq0 = 0.f, sq6 = 0.f;          // psq partials (fp32)

    #pragma unroll 6
    for (int s = 0; s < 12; ++s) {
        float4 a0 = *(const float4*)(arow + s * 32);
        float4 a1 = *(const float4*)(arow + s * 32 + 4);
        float4 b0 = *(const float4*)(brow + s * 32);
        float4 b1 = *(const float4*)(brow + s * 32 + 4);
        float4 c0 = *(const float4*)(brw6 + s * 32);
        float4 c1 = *(const float4*)(brw6 + s * 32 + 4);
        short8 A  = cvt8(a0, a1);
        short8 Bv = cvt8(b0, b1);
        short8 B6 = cvt8(c0, c1);
        sq0 += sq8(b0, b1);
        sq6 += sq8(c0, c1);
        acc0 = __builtin_amdgcn_mfma_f32_16x16x32_bf16(A, Bv, acc0, 0, 0, 0);
        acc1 = __builtin_amdgcn_mfma_f32_16x16x32_bf16(A, B6, acc1, 0, 0, 0);
    }
    // fold the 4 kq-quads (lanes n, n+16, n+32, n+48 share proto n)
    sq0 += __shfl_xor(sq0, 16, 64); sq0 += __shfl_xor(sq0, 32, 64);
    sq6 += __shfl_xor(sq6, 16, 64); sq6 += __shfl_xor(sq6, 32, 64);

    {
        float* s = scL + (wv * 64 + lane) * 11;
        #pragma unroll
        for (int r = 0; r < 4; ++r) { s[r] = acc0[r]; s[r + 4] = acc1[r]; }
        s[8] = sq0; s[9] = sq6;
    }
    __syncthreads();

    // ---- epilogue: wave 0 -> tile0 (waves 0+1), wave 1 -> tile1 (waves 2+3) ----
    if (wv < 2) {
        const float* sa = scL + ((wv * 2)     * 64 + lane) * 11;
        const float* sb = scL + ((wv * 2 + 1) * 64 + lane) * 11;
        float f0[4], f1[4];
        #pragma unroll
        for (int r = 0; r < 4; ++r) {
            f0[r] = sa[r]     + sb[r];
            f1[r] = sa[r + 4] + sb[r + 4];
        }
        const float fsq0 = sa[8] + sb[8];
        const float fsq6 = sa[9] + sb[9];
        const int pe = psl * 32 + wv * 16;   // this tile's global patch base

        float a_[4], a16[4];
        #pragma unroll
        for (int r = 0; r < 4; ++r) {
            float l0  = 2.f * f0[r] - fsq0;
            float l16 = 2.f * f1[r] - fsq6;
            float mx = l0;
            #pragma unroll
            for (int o = 1; o < 16; o <<= 1) mx = fmaxf(mx, __shfl_xor(mx, o, 64));
            mx = fmaxf(mx, l16);
            float e0  = __expf(l0 - mx);
            float e16 = __expf(l16 - mx);
            float sum = e0;
            #pragma unroll
            for (int o = 1; o < 16; o <<= 1) sum += __shfl_xor(sum, o, 64);
            sum += e16;
            const float inv = 1.f / sum;
            a_[r]  = e0 * inv;
            a16[r] = e16 * inv;
        }

        *(float4*)(A_out + ((size_t)b * K1 + n) * P + pe + kq * 4) =
            make_float4(a_[0], a_[1], a_[2], a_[3]);
        if (n == 0)
            *(float4*)(A_out + ((size_t)b * K1 + 16) * P + pe + kq * 4) =
                make_float4(a16[0], a16[1], a16[2], a16[3]);

        const float invP = 1.f / (float)P;
        #pragma unroll
        for (int r = 0; r < 4; ++r)
            as_[(wv * 16 + kq * 4 + r) * KFG + n] = a_[r] * invP;
    }
    __syncthreads();

    // ---- pool: thread owns d = t, t+256, t+512; 32 block-local patches ----
    float accp[3][KFG];
    #pragma unroll
    for (int j = 0; j < 3; ++j)
        #pragma unroll
        for (int k = 0; k < KFG; ++k) accp[j][k] = 0.f;

    const float* xb = x + ((size_t)(b * P + psl * 32)) * D;
    for (int p = 0; p < 32; ++p) {
        f32x4 A0 = *(const f32x4*)(as_ + p * 16);
        f32x4 A1 = *(const f32x4*)(as_ + p * 16 + 4);
        f32x4 A2 = *(const f32x4*)(as_ + p * 16 + 8);
        f32x4 A3 = *(const f32x4*)(as_ + p * 16 + 12);
        float av[KFG] = { A0[0],A0[1],A0[2],A0[3], A1[0],A1[1],A1[2],A1[3],
                          A2[0],A2[1],A2[2],A2[3], A3[0],A3[1],A3[2],A3[3] };
        #pragma unroll
        for (int j = 0; j < 3; ++j) {
            float xv = xb[(size_t)p * D + t + j * 256];
            #pragma unroll
            for (int k = 0; k < KFG; ++k) accp[j][k] += av[k] * xv;
        }
    }
    float* o = vpart + ((size_t)(psl * B + b) * KFG) * D;
    #pragma unroll
    for (int j = 0; j < 3; ++j)
        #pragma unroll
        for (int k = 0; k < KFG; ++k)
            o[(size_t)k * D + t + j * 256] = accp[j][k];
}

// ================= K2: reduce 18 p-splits + LayerNorm; write vnorm + vT =================
// grid (16 k, 32 b) x 256; thread owns 3 d's.
__global__ __launch_bounds__(256) void k_ln(const float* __restrict__ vpart,
                                            const float* __restrict__ gamma,
                                            const float* __restrict__ beta,
                                            float* __restrict__ vnorm_out,
                                            float* __restrict__ vT) {
    const int k = blockIdx.x, b = blockIdx.y, t = threadIdx.x;
    const int lane = t & 63, wv = t >> 6;

    float v[3]; float s1 = 0.f, s2 = 0.f;
    #pragma unroll
    for (int j = 0; j < 3; ++j) {
        const int d = t + j * 256;
        float s = 0.f;
        #pragma unroll
        for (int psl = 0; psl < 18; ++psl)
            s += vpart[((size_t)(psl * B + b) * KFG + k) * D + d];
        v[j] = s; s1 += s; s2 += s * s;
    }
    #pragma unroll
    for (int o = 1; o < 64; o <<= 1) {
        s1 += __shfl_xor(s1, o, 64);
        s2 += __shfl_xor(s2, o, 64);
    }
    __shared__ float r1[4], r2[4];
    if (lane == 0) { r1[wv] = s1; r2[wv] = s2; }
    __syncthreads();
    s1 = r1[0] + r1[1] + r1[2] + r1[3];
    s2 = r2[0] + r2[1] + r2[2] + r2[3];

    const float mean = s1 * (1.f / (float)D);
    const float var  = s2 * (1.f / (float)D) - mean * mean;
    const float rs   = rsqrtf(var + LN_EPS);

    #pragma unroll
    for (int j = 0; j < 3; ++j) {
        const int d = t + j * 256;
        float vn = (v[j] - mean) * rs * gamma[d] + beta[d];
        vnorm_out[((size_t)b * KFG + k) * D + d] = vn;
        vT[((size_t)b * D + d) * KFG + k] = vn;   // k-contiguous for k_cls s_loads
    }
}

// ================= K3: classifier + bias + agg, fused =================
// grid 64 = (b, class-half) x 512 thr (8 waves). Thread (cq = t>>7, cl = t&127):
// d-quarter cq of class ch*100+cl. LDS 32 KB reduce, then 100 threads finalize.
__global__ __launch_bounds__(512) void k_cls(const float* __restrict__ vT,
                                             const float* __restrict__ W,
                                             const float* __restrict__ bcls,
                                             float* __restrict__ parts_out,
                                             float* __restrict__ agg_out) {
    __shared__ float lp[4 * 128 * KFG];   // 32 KB
    const int b = blockIdx.x >> 1, ch = blockIdx.x & 1;
    const int t = threadIdx.x;
    const int cq = t >> 7, cl = t & 127;
    const int c = ch * 100 + (cl < 100 ? cl : 99);   // clamp keeps loads in-bounds

    const float* vt = vT + ((size_t)b * D + cq * 192) * KFG;   // wave-uniform rows
    const float* Wp = W + (size_t)(cq * 192) * C + c;

    float acc[KFG];
    #pragma unroll
    for (int k = 0; k < KFG; ++k) acc[k] = 0.f;

    #pragma unroll 4
    for (int i = 0; i < 192; ++i) {
        float wl = Wp[(size_t)i * C];                 // coalesced across lanes
        f32x4 V0 = *(const f32x4*)(vt + i * 16);      // uniform -> s_load
        f32x4 V1 = *(const f32x4*)(vt + i * 16 + 4);
        f32x4 V2 = *(const f32x4*)(vt + i * 16 + 8);
        f32x4 V3 = *(const f32x4*)(vt + i * 16 + 12);
        acc[0]  += V0[0] * wl; acc[1]  += V0[1] * wl; acc[2]  += V0[2] * wl; acc[3]  += V0[3] * wl;
        acc[4]  += V1[0] * wl; acc[5]  += V1[1] * wl; acc[6]  += V1[2] * wl; acc[7]  += V1[3] * wl;
        acc[8]  += V2[0] * wl; acc[9]  += V2[1] * wl; acc[10] += V2[2] * wl; acc[11] += V2[3] * wl;
        acc[12] += V3[0] * wl; acc[13] += V3[1] * wl; acc[14] += V3[2] * wl; acc[15] += V3[3] * wl;
    }
    #pragma unroll
    for (int k = 0; k < KFG; ++k) lp[(cq * 128 + cl) * KFG + k] = acc[k];
    __syncthreads();

    if (t < 100) {
        const int cw = ch * 100 + t;
        const float bc = bcls[cw];
        float s_agg = 0.f;
        #pragma unroll
        for (int k = 0; k < KFG; ++k) {
            float s = bc + lp[(0 * 128 + t) * KFG + k] + lp[(1 * 128 + t) * KFG + k]
                         + lp[(2 * 128 + t) * KFG + k] + lp[(3 * 128 + t) * KFG + k];
            parts_out[((size_t)b * KFG + k) * C + cw] = s;
            s_agg += s;
        }
        agg_out[(size_t)b * C + cw] = s_agg * (1.f / (float)KFG);
    }
}

extern "C" void kernel_launch(void* const* d_in, const int* in_sizes, int n_in,
                              void* d_out, int out_size, void* d_ws, size_t ws_size,
                              hipStream_t stream) {
    const float* x     = (const float*)d_in[0];   // (32,24,24,768)
    const float* proto = (const float*)d_in[1];   // (17,768)
    const float* gamma = (const float*)d_in[2];   // (768)
    const float* beta  = (const float*)d_in[3];   // (768)
    const float* W     = (const float*)d_in[4];   // (768,200)
    const float* bcls  = (const float*)d_in[5];   // (200)

    float* out = (float*)d_out;
    float* A_out     = out;                       // 32*17*576   = 313344
    float* vnorm_out = out + 313344;              // 32*16*768   = 393216
    float* parts_out = out + 706560;              // 32*16*200   = 102400
    float* agg_out   = out + 808960;              // 32*200      = 6400

    float* ws = (float*)d_ws;
    float* vpart = ws;                             // 18*32*16*768 = 7077888
    float* vT    = vpart + 7077888;                // 32*768*16    = 393216

    hipLaunchKernelGGL(k_front, dim3(18, B),  dim3(256), 0, stream, x, proto, A_out, vpart);
    hipLaunchKernelGGL(k_ln,    dim3(KFG, B), dim3(256), 0, stream, vpart, gamma, beta, vnorm_out, vT);
    hipLaunchKernelGGL(k_cls,   dim3(64),     dim3(512), 0, stream, vT, W, bcls, parts_out, agg_out);
}

// Round 9
// 139.263 us; speedup vs baseline: 3.7384x; 1.3273x over previous
//
#include <hip/hip_runtime.h>
#include <hip/hip_bf16.h>

// Problem constants
#define B    32
#define P    576     // 24*24 patches
#define D    768
#define K1   17      // K+1 prototypes
#define KFG  16
#define C    200
#define LN_EPS 1e-6f

typedef __attribute__((ext_vector_type(8))) short short8;   // 8 bf16 (4 VGPRs)
typedef __attribute__((ext_vector_type(4))) float f32x4;

// packed fp32x8 -> bf16x8 via v_cvt_pk_bf16_f32
__device__ inline short8 cvt8(float4 a, float4 b) {
    union { unsigned u[4]; short8 s; } r;
    union { __hip_bfloat162 h; unsigned u; } c;
    c.h = __float22bfloat162_rn(make_float2(a.x, a.y)); r.u[0] = c.u;
    c.h = __float22bfloat162_rn(make_float2(a.z, a.w)); r.u[1] = c.u;
    c.h = __float22bfloat162_rn(make_float2(b.x, b.y)); r.u[2] = c.u;
    c.h = __float22bfloat162_rn(make_float2(b.z, b.w)); r.u[3] = c.u;
    return r.s;
}
__device__ inline float sq8(float4 a, float4 b) {
    return a.x*a.x + a.y*a.y + a.z*a.z + a.w*a.w
         + b.x*b.x + b.y*b.y + b.z*b.z + b.w*b.w;
}

// ================= K1: dots (bf16 MFMA, K-split 4) + softmax =================
// grid (36 tiles, 32 b) x 256 (4 waves). Block = one 16-patch tile; wave wv owns
// K-range [wv*192, wv*192+192) = 6 MFMA steps. 4608 waves (~18/CU) for latency
// hiding. psq accumulated in-loop from fp32 protos. LDS 11.3 KB.
__global__ __launch_bounds__(256) void k_dots(const float* __restrict__ x,
                                              const float* __restrict__ proto,
                                              float* __restrict__ A_out,
                                              float* __restrict__ apool) {
    __shared__ float scL[4 * 64 * 11];   // [wave][lane][acc0:4|acc1:4|sq0|sq6], stride 11
    const int tile = blockIdx.x, b = blockIdx.y;
    const int t = threadIdx.x, wv = t >> 6, lane = t & 63;
    const int n = lane & 15, kq = lane >> 4;
    const int p0 = tile * 16;

    const float* arow = x     + ((size_t)(b * P + p0 + n)) * D + wv * 192 + kq * 8;
    const float* brow = proto + (size_t)n  * D + wv * 192 + kq * 8;
    const float* brw6 = proto + (size_t)16 * D + wv * 192 + kq * 8;

    f32x4 acc0 = {0.f, 0.f, 0.f, 0.f};   // protos 0..15, this K-quarter
    f32x4 acc1 = {0.f, 0.f, 0.f, 0.f};   // proto 16 (broadcast B)
    float sq0 = 0.f, sq6 = 0.f;          // psq partials (fp32-exact)

    #pragma unroll
    for (int s = 0; s < 6; ++s) {
        float4 a0 = *(const float4*)(arow + s * 32);
        float4 a1 = *(const float4*)(arow + s * 32 + 4);
        float4 b0 = *(const float4*)(brow + s * 32);
        float4 b1 = *(const float4*)(brow + s * 32 + 4);
        float4 c0 = *(const float4*)(brw6 + s * 32);
        float4 c1 = *(const float4*)(brw6 + s * 32 + 4);
        short8 A  = cvt8(a0, a1);
        short8 Bv = cvt8(b0, b1);
        short8 B6 = cvt8(c0, c1);
        sq0 += sq8(b0, b1);
        sq6 += sq8(c0, c1);
        acc0 = __builtin_amdgcn_mfma_f32_16x16x32_bf16(A, Bv, acc0, 0, 0, 0);
        acc1 = __builtin_amdgcn_mfma_f32_16x16x32_bf16(A, B6, acc1, 0, 0, 0);
    }
    // fold the 4 kq-quads (lanes n, n+16, n+32, n+48 share proto n)
    sq0 += __shfl_xor(sq0, 16, 64); sq0 += __shfl_xor(sq0, 32, 64);
    sq6 += __shfl_xor(sq6, 16, 64); sq6 += __shfl_xor(sq6, 32, 64);

    {
        float* s = scL + (wv * 64 + lane) * 11;
        #pragma unroll
        for (int r = 0; r < 4; ++r) { s[r] = acc0[r]; s[r + 4] = acc1[r]; }
        s[8] = sq0; s[9] = sq6;
    }
    __syncthreads();
    if (wv != 0) return;

    // ---- reduce 4 K-quarters (wave 0) ----
    float f0[4], f1[4]; float fsq0 = 0.f, fsq6 = 0.f;
    #pragma unroll
    for (int r = 0; r < 4; ++r) { f0[r] = 0.f; f1[r] = 0.f; }
    #pragma unroll
    for (int w = 0; w < 4; ++w) {
        const float* s = scL + (w * 64 + lane) * 11;
        #pragma unroll
        for (int r = 0; r < 4; ++r) { f0[r] += s[r]; f1[r] += s[r + 4]; }
        fsq0 += s[8]; fsq6 += s[9];
    }

    // ---- softmax per (kq, r) across n (xor 1,2,4,8 stays within quad) ----
    float a_[4], a16[4];
    #pragma unroll
    for (int r = 0; r < 4; ++r) {
        float l0  = 2.f * f0[r] - fsq0;
        float l16 = 2.f * f1[r] - fsq6;
        float mx = l0;
        #pragma unroll
        for (int o = 1; o < 16; o <<= 1) mx = fmaxf(mx, __shfl_xor(mx, o, 64));
        mx = fmaxf(mx, l16);
        float e0  = __expf(l0 - mx);
        float e16 = __expf(l16 - mx);
        float sum = e0;
        #pragma unroll
        for (int o = 1; o < 16; o <<= 1) sum += __shfl_xor(sum, o, 64);
        sum += e16;
        const float inv = 1.f / sum;
        a_[r]  = e0 * inv;
        a16[r] = e16 * inv;
    }

    *(float4*)(A_out + ((size_t)b * K1 + n) * P + p0 + kq * 4) =
        make_float4(a_[0], a_[1], a_[2], a_[3]);
    if (n == 0)
        *(float4*)(A_out + ((size_t)b * K1 + 16) * P + p0 + kq * 4) =
            make_float4(a16[0], a16[1], a16[2], a16[3]);

    const float invP = 1.f / (float)P;
    #pragma unroll
    for (int r = 0; r < 4; ++r)
        apool[((size_t)b * P + p0 + kq * 4 + r) * KFG + n] = a_[r] * invP;
}

// ================= K2: fp32 pooling; a-rows via provably-uniform s_loads =================
// grid (3 dchunk, 6 psplit of 96, 32 b) x 256; thread owns one d. ZERO LDS.
// x is L3-resident after k_dots; apool rows are blockIdx-uniform -> s_load_dwordx16.
__global__ __launch_bounds__(256, 4) void k_pool(const float* __restrict__ x,
                                                 const float* __restrict__ apool,
                                                 float* __restrict__ vpart) {
    const int dc = blockIdx.x, psl = blockIdx.y, b = blockIdx.z;
    const int t = threadIdx.x;
    const int d = dc * 256 + t;

    const float* aw = apool + ((size_t)b * P + psl * 96) * KFG;   // uniform (blockIdx)
    const float* xp = x + ((size_t)b * P + psl * 96) * D + d;

    float acc[KFG];
    #pragma unroll
    for (int k = 0; k < KFG; ++k) acc[k] = 0.f;

    #pragma unroll 4
    for (int p = 0; p < 96; ++p) {
        float xv = xp[(size_t)p * D];
        f32x4 A0 = *(const f32x4*)(aw + p * 16);        // -> s_load_dwordx16
        f32x4 A1 = *(const f32x4*)(aw + p * 16 + 4);
        f32x4 A2 = *(const f32x4*)(aw + p * 16 + 8);
        f32x4 A3 = *(const f32x4*)(aw + p * 16 + 12);
        acc[0]  += A0[0] * xv; acc[1]  += A0[1] * xv; acc[2]  += A0[2] * xv; acc[3]  += A0[3] * xv;
        acc[4]  += A1[0] * xv; acc[5]  += A1[1] * xv; acc[6]  += A1[2] * xv; acc[7]  += A1[3] * xv;
        acc[8]  += A2[0] * xv; acc[9]  += A2[1] * xv; acc[10] += A2[2] * xv; acc[11] += A2[3] * xv;
        acc[12] += A3[0] * xv; acc[13] += A3[1] * xv; acc[14] += A3[2] * xv; acc[15] += A3[3] * xv;
    }
    float* o = vpart + ((size_t)(psl * B + b) * KFG) * D + d;
    #pragma unroll
    for (int k = 0; k < KFG; ++k) o[(size_t)k * D] = acc[k];
}

// ================= K3: reduce 6 p-splits + LayerNorm; write vnorm + vT =================
// grid (16 k, 32 b) x 256; thread owns 3 d's.
__global__ __launch_bounds__(256) void k_ln(const float* __restrict__ vpart,
                                            const float* __restrict__ gamma,
                                            const float* __restrict__ beta,
                                            float* __restrict__ vnorm_out,
                                            float* __restrict__ vT) {
    const int k = blockIdx.x, b = blockIdx.y, t = threadIdx.x;
    const int lane = t & 63, wv = t >> 6;

    float v[3]; float s1 = 0.f, s2 = 0.f;
    #pragma unroll
    for (int j = 0; j < 3; ++j) {
        const int d = t + j * 256;
        float s = 0.f;
        #pragma unroll
        for (int psl = 0; psl < 6; ++psl)
            s += vpart[((size_t)(psl * B + b) * KFG + k) * D + d];
        v[j] = s; s1 += s; s2 += s * s;
    }
    #pragma unroll
    for (int o = 1; o < 64; o <<= 1) {
        s1 += __shfl_xor(s1, o, 64);
        s2 += __shfl_xor(s2, o, 64);
    }
    __shared__ float r1[4], r2[4];
    if (lane == 0) { r1[wv] = s1; r2[wv] = s2; }
    __syncthreads();
    s1 = r1[0] + r1[1] + r1[2] + r1[3];
    s2 = r2[0] + r2[1] + r2[2] + r2[3];

    const float mean = s1 * (1.f / (float)D);
    const float var  = s2 * (1.f / (float)D) - mean * mean;
    const float rs   = rsqrtf(var + LN_EPS);

    #pragma unroll
    for (int j = 0; j < 3; ++j) {
        const int d = t + j * 256;
        float vn = (v[j] - mean) * rs * gamma[d] + beta[d];
        vnorm_out[((size_t)b * KFG + k) * D + d] = vn;
        vT[((size_t)b * D + d) * KFG + k] = vn;   // k-contiguous for k_cls s_loads
    }
}

// ================= K4: classifier partial GEMV; vT rows via uniform s_loads =================
// grid (8 dq, 32 b) x 256; thread = class c. dq/b from blockIdx -> provably uniform.
__global__ __launch_bounds__(256) void k_cls(const float* __restrict__ vT,
                                             const float* __restrict__ W,
                                             float* __restrict__ lpart) {
    const int dq = blockIdx.x, b = blockIdx.y;
    const int c = threadIdx.x;
    const int cc = c < C ? c : (C - 1);

    const float* vt = vT + ((size_t)b * D + dq * 96) * KFG;   // uniform (blockIdx)
    const float* Wp = W + (size_t)dq * 96 * C + cc;

    float acc[KFG];
    #pragma unroll
    for (int k = 0; k < KFG; ++k) acc[k] = 0.f;

    #pragma unroll 4
    for (int i = 0; i < 96; ++i) {
        float wl = Wp[(size_t)i * C];                 // coalesced across lanes
        f32x4 V0 = *(const f32x4*)(vt + i * 16);      // -> s_load_dwordx16
        f32x4 V1 = *(const f32x4*)(vt + i * 16 + 4);
        f32x4 V2 = *(const f32x4*)(vt + i * 16 + 8);
        f32x4 V3 = *(const f32x4*)(vt + i * 16 + 12);
        acc[0]  += V0[0] * wl; acc[1]  += V0[1] * wl; acc[2]  += V0[2] * wl; acc[3]  += V0[3] * wl;
        acc[4]  += V1[0] * wl; acc[5]  += V1[1] * wl; acc[6]  += V1[2] * wl; acc[7]  += V1[3] * wl;
        acc[8]  += V2[0] * wl; acc[9]  += V2[1] * wl; acc[10] += V2[2] * wl; acc[11] += V2[3] * wl;
        acc[12] += V3[0] * wl; acc[13] += V3[1] * wl; acc[14] += V3[2] * wl; acc[15] += V3[3] * wl;
    }
    if (c < C) {
        float* o = lpart + ((size_t)(dq * B + b) * KFG) * C + c;
        #pragma unroll
        for (int k = 0; k < KFG; ++k) o[(size_t)k * C] = acc[k];
    }
}

// ================= K5: combine d-splits + bias; logits_parts + logits_agg =================
__global__ __launch_bounds__(256) void k_comb(const float* __restrict__ lpart,
                                              const float* __restrict__ bcls,
                                              float* __restrict__ parts,
                                              float* __restrict__ agg) {
    const int b = blockIdx.x, c = threadIdx.x;
    if (c >= C) return;
    const float bc = bcls[c];
    float s_agg = 0.f;
    #pragma unroll
    for (int k = 0; k < KFG; ++k) {
        float s = bc;
        #pragma unroll
        for (int dq = 0; dq < 8; ++dq)
            s += lpart[((size_t)(dq * B + b) * KFG + k) * C + c];
        parts[((size_t)b * KFG + k) * C + c] = s;
        s_agg += s;
    }
    agg[(size_t)b * C + c] = s_agg * (1.f / (float)KFG);
}

extern "C" void kernel_launch(void* const* d_in, const int* in_sizes, int n_in,
                              void* d_out, int out_size, void* d_ws, size_t ws_size,
                              hipStream_t stream) {
    const float* x     = (const float*)d_in[0];   // (32,24,24,768)
    const float* proto = (const float*)d_in[1];   // (17,768)
    const float* gamma = (const float*)d_in[2];   // (768)
    const float* beta  = (const float*)d_in[3];   // (768)
    const float* W     = (const float*)d_in[4];   // (768,200)
    const float* bcls  = (const float*)d_in[5];   // (200)

    float* out = (float*)d_out;
    float* A_out     = out;                       // 32*17*576   = 313344
    float* vnorm_out = out + 313344;              // 32*16*768   = 393216
    float* parts_out = out + 706560;              // 32*16*200   = 102400
    float* agg_out   = out + 808960;              // 32*200      = 6400

    float* ws = (float*)d_ws;
    float* apool = ws;                             // 32*576*16   = 294912
    float* vpart = apool + 294912;                 // 6*32*16*768 = 2359296
    float* vT    = vpart + 2359296;                // 32*768*16   = 393216
    float* lpart = vT + 393216;                    // 8*32*16*200 = 819200

    hipLaunchKernelGGL(k_dots, dim3(36, B),   dim3(256), 0, stream, x, proto, A_out, apool);
    hipLaunchKernelGGL(k_pool, dim3(3, 6, B), dim3(256), 0, stream, x, apool, vpart);
    hipLaunchKernelGGL(k_ln,   dim3(KFG, B),  dim3(256), 0, stream, vpart, gamma, beta, vnorm_out, vT);
    hipLaunchKernelGGL(k_cls,  dim3(8, B),    dim3(256), 0, stream, vT, W, lpart);
    hipLaunchKernelGGL(k_comb, dim3(B),       dim3(256), 0, stream, lpart, bcls, parts_out, agg_out);
}